// Round 1
// baseline (342.451 us; speedup 1.0000x reference)
//
#include <hip/hip_runtime.h>
#include <math.h>

#define B 64
#define V 64
#define NN 16384
#define RR 32
#define HIDN 128
#define BIGV 1000000000.0f

// ws layout: [0,256) bytes: per-b compaction counters (B ints).
//            [256, 256 + B*NN*4): compacted index list, list[b*NN + k] = n.

// Kernel 1: evaluate m[b,n] over the (<= t+1) relevant table rows and compact
// the surviving n's into a per-b list. Grid: (16 slices, B). 256 thr, int4 loads.
__global__ void k_compact(const int* __restrict__ tables,
                          const int* __restrict__ base_obs,
                          const int* __restrict__ actions,
                          const int* __restrict__ responses,
                          const int* __restrict__ t_ptr,
                          int* __restrict__ cnt,
                          int* __restrict__ list,
                          int T)
{
    const int b = blockIdx.y;
    const int t = t_ptr[0];
    const int n0 = blockIdx.x * (NN / 16) + threadIdx.x * 4; // 16 slices, 256 thr, 4/thr
    const int base = base_obs[b];
    const int4 tv = *(const int4*)(tables + (size_t)b * V * NN + n0);
    int m0 = (tv.x == base), m1 = (tv.y == base), m2 = (tv.z == base), m3 = (tv.w == base);
    for (int i = 0; i < t; ++i) {
        const int a = actions[b * T + i];
        if (a == V) continue;                    // stop action: m unchanged, wave-uniform
        const int resp = responses[b * T + i];
        const int4 lv = *(const int4*)(tables + ((size_t)b * V + a) * NN + n0);
        m0 &= (lv.x == resp); m1 &= (lv.y == resp); m2 &= (lv.z == resp); m3 &= (lv.w == resp);
    }
    // sparse: compiler wave-aggregates atomicAdd(p,1); order in list is irrelevant
    if (m0) { int i = atomicAdd(&cnt[b], 1); list[b * NN + i] = n0; }
    if (m1) { int i = atomicAdd(&cnt[b], 1); list[b * NN + i] = n0 + 1; }
    if (m2) { int i = atomicAdd(&cnt[b], 1); list[b * NN + i] = n0 + 2; }
    if (m3) { int i = atomicAdd(&cnt[b], 1); list[b * NN + i] = n0 + 3; }
}

// Kernel 2: per-b block. Thread v (<64) builds counts[r]/pres-mask[r] for cell
// (b,v) from the K_b survivors, thread 64 builds the stop column, then threads
// 0..64 run the fused 2->128->1 MLP with exact GELU.
__global__ void k_feat(const int* __restrict__ tables,
                       const int* __restrict__ sigma,
                       const int* __restrict__ actions,
                       const int* __restrict__ t_ptr,
                       const int* __restrict__ cnt,
                       const int* __restrict__ list,
                       const float* __restrict__ W1,
                       const float* __restrict__ b1,
                       const float* __restrict__ W2,
                       const float* __restrict__ b2,
                       float* __restrict__ out,
                       int T)
{
    const int b = blockIdx.x;
    const int tid = threadIdx.x;                 // 128 threads
    // [r][v] layout: addr = r*64+v -> bank = v%32 -> conflict-free (2-way)
    __shared__ unsigned s_counts[RR * V];
    __shared__ unsigned s_mask[RR * V];
    __shared__ float s_feat[(V + 1) * 2];

    for (int i = tid; i < RR * V; i += 128) { s_counts[i] = 0u; s_mask[i] = 0u; }
    __syncthreads();

    const int K = cnt[b];
    const int t = t_ptr[0];
    const int* blist = list + b * NN;
    const int* bsig  = sigma + (size_t)b * NN;

    if (tid < V) {
        const int v = tid;
        const int* rowv = tables + ((size_t)b * V + v) * NN;
        for (int k = 0; k < K; ++k) {
            const int n = blist[k];              // wave-uniform per k
            const int r = rowv[n];               // gather (uncoalesced but tiny K)
            const int y = bsig[n];               // uniform broadcast
            s_counts[r * V + v] += 1u;           // thread v owns column v: no race
            s_mask[r * V + v] |= (1u << y);
        }
    } else if (tid == V) {
        unsigned pm = 0u;
        for (int k = 0; k < K; ++k) pm |= (1u << bsig[blist[k]]);
        s_feat[V * 2 + 0] = (float)__popc(pm);   // stop_amb
        s_feat[V * 2 + 1] = (float)K;            // total0
    }
    __syncthreads();

    if (tid < V) {
        const int v = tid;
        const float safe = (K > 0) ? (float)K : 1.0f;
        float sz = 0.f, amb = 0.f;
        for (int r = 0; r < RR; ++r) {
            const float c = (float)s_counts[r * V + v];
            const float u = (float)__popc(s_mask[r * V + v]);
            sz += c * c;
            amb += c * u;
        }
        sz /= safe; amb /= safe;
        bool forb = (v == 0);
        for (int i = 0; i < t; ++i)
            if (actions[b * T + i] == v) forb = true;   // a==V never matches v<64
        if (forb) { sz = BIGV; amb = BIGV; }
        s_feat[v * 2 + 0] = amb;
        s_feat[v * 2 + 1] = sz;
    }
    __syncthreads();

    if (tid <= V) {
        float f0 = 0.f, f1 = 0.f;
        if (K > 0) { f0 = s_feat[tid * 2 + 0]; f1 = s_feat[tid * 2 + 1]; }
        float acc = b2[0];
        for (int j = 0; j < HIDN; ++j) {
            const float x = f0 * W1[j] + f1 * W1[HIDN + j] + b1[j];
            const float g = 0.5f * x * (1.0f + erff(x * 0.70710678118654752f));
            acc = fmaf(g, W2[j], acc);
        }
        out[b * (V + 1) + tid] = acc;
    }
}

extern "C" void kernel_launch(void* const* d_in, const int* in_sizes, int n_in,
                              void* d_out, int out_size, void* d_ws, size_t ws_size,
                              hipStream_t stream) {
    const int* tables    = (const int*)d_in[0];
    const int* sigma     = (const int*)d_in[1];
    const int* base_obs  = (const int*)d_in[2];
    const int* actions   = (const int*)d_in[3];
    const int* responses = (const int*)d_in[4];
    const float* W1      = (const float*)d_in[5];
    const float* b1      = (const float*)d_in[6];
    const float* W2      = (const float*)d_in[7];
    const float* b2      = (const float*)d_in[8];
    const int* t_ptr     = (const int*)d_in[9];
    float* out = (float*)d_out;

    const int T = in_sizes[3] / B;   // actions is [B,T]

    int* cnt  = (int*)d_ws;
    int* list = (int*)((char*)d_ws + 256);

    // ws is poisoned to 0xAA before every launch: zero the counters.
    hipMemsetAsync(cnt, 0, B * sizeof(int), stream);

    dim3 g1(16, B);
    k_compact<<<g1, 256, 0, stream>>>(tables, base_obs, actions, responses,
                                      t_ptr, cnt, list, T);
    k_feat<<<B, 128, 0, stream>>>(tables, sigma, actions, t_ptr, cnt, list,
                                  W1, b1, W2, b2, out, T);
}